// Round 8
// baseline (399.740 us; speedup 1.0000x reference)
//
#include <hip/hip_runtime.h>

#define BATCH 256
#define SEQ   2048
#define NC    32
#define EMB   2048
#define NT    32          // SEQ / BK, BK = 64

typedef unsigned short ushort_t;
using f32x4  = __attribute__((ext_vector_type(4))) float;
using bf16x8 = __attribute__((ext_vector_type(8))) short;

using u32_gl = __attribute__((address_space(1))) const unsigned int;
using u32_ld = __attribute__((address_space(3))) unsigned int;

__device__ __forceinline__ unsigned int f2bf(float f) {
  unsigned int u = __float_as_uint(f);
  u += 0x7FFFu + ((u >> 16) & 1u);   // RNE (finite inputs)
  return u >> 16;
}

#define SB() __builtin_amdgcn_sched_barrier(0)

// ---------------------------------------------------------------------------
// x: (B, S, C) f32  ->  xT: (C, B, S) bf16
// ---------------------------------------------------------------------------
__global__ __launch_bounds__(256) void transpose_x_kernel(
    const float* __restrict__ x, ushort_t* __restrict__ xT) {
  __shared__ float tile[64][33];
  const int b  = blockIdx.x >> 5;
  const int st = blockIdx.x & 31;
  const int t  = threadIdx.x;
  const float* src = x + ((size_t)b * SEQ + (size_t)st * 64) * NC;
#pragma unroll
  for (int i = 0; i < 2; ++i) {
    int idx = t + i * 256;
    float4 v = reinterpret_cast<const float4*>(src)[idx];
    int s = idx >> 3;
    int c = (idx & 7) * 4;
    tile[s][c + 0] = v.x; tile[s][c + 1] = v.y;
    tile[s][c + 2] = v.z; tile[s][c + 3] = v.w;
  }
  __syncthreads();
  const int c  = t >> 3;
  const int si = (t & 7) * 8;
  unsigned int q[4];
#pragma unroll
  for (int p = 0; p < 4; ++p) {
    unsigned int h0 = f2bf(tile[si + 2 * p + 0][c]);
    unsigned int h1 = f2bf(tile[si + 2 * p + 1][c]);
    q[p] = h0 | (h1 << 16);
  }
  ushort_t* dst = xT + (size_t)c * (BATCH * SEQ) + (size_t)b * SEQ + st * 64 + si;
  *reinterpret_cast<uint4*>(dst) = make_uint4(q[0], q[1], q[2], q[3]);
}

// ---------------------------------------------------------------------------
// H1 test: BM=256 / BN=256 / BK=64 (W row segments = 1 KB contiguous).
// R3's exact 2-barrier counted-vmcnt schedule. 512 thr = 8 waves (4m x 2e),
// each 64m x 128e -> acc[4][8]. LDS: A dbuf 2x32 KB + B dbuf 2x32 KB = 128 KB.
// W loads: wave = one full 1 KB row per instr (tid&63 lanes x f32x4);
//   thread owns 2 batches x (4 consecutive s-rows x 4 e) -> clean uint2
//   converts into Bt[e][s] rows (128 B), R3's (e&7) key (2-way reads).
// Steady vmem queue entering iter t: [W(t):8, A(t):4] = 12.
// ---------------------------------------------------------------------------
template <int P>
__device__ __forceinline__ void gemm_iter(
    int t, const ushort_t* __restrict__ xTc, const float* __restrict__ Wc,
    char* Alds, char* Blds, f32x4 (&wv)[2][8], f32x4 (&acc)[4][8],
    int tid, int wr, int wc, int g, int lm, int e0) {
  const int s4  = tid >> 6;          // 0..7  (wave id = s-row group)
  const int e16 = tid & 63;          // 0..63 (e-quad within row)

  // ---- step 0: issue W(t+1): 2 batches x 4 rows, 1 KB/row/instr ----
  {
    const int tn = (t + 1) & (NT - 1);
    const float* wp = Wc + (size_t)(tn * 64) * EMB + e0 + e16 * 4;
#pragma unroll
    for (int q = 0; q < 2; ++q)
#pragma unroll
      for (int j = 0; j < 4; ++j)
        wv[P ^ 1][q * 4 + j] =
            *reinterpret_cast<const f32x4*>(wp + (size_t)((s4 + 8 * q) * 4 + j) * EMB);
  }
  SB();

  // ---- step 1: W(t) ready; leave [A(t):4, W(t+1):8] in flight ----
  asm volatile("s_waitcnt vmcnt(12)" ::: "memory");

  // ---- step 2: convert W(t) -> Blds[P] (rows e, 128 B, key (e&7)) ----
#pragma unroll
  for (int q = 0; q < 2; ++q)
#pragma unroll
    for (int i = 0; i < 4; ++i) {
      const int e = e16 * 4 + i;
      unsigned int lo = f2bf(wv[P][q * 4 + 0][i]) | (f2bf(wv[P][q * 4 + 1][i]) << 16);
      unsigned int hi = f2bf(wv[P][q * 4 + 2][i]) | (f2bf(wv[P][q * 4 + 3][i]) << 16);
      int byte = (e * 128 + (s4 + 8 * q) * 8) ^ ((e & 7) << 4);
      *reinterpret_cast<uint2*>(Blds + P * 32768 + byte) = make_uint2(lo, hi);
    }
  asm volatile("s_waitcnt lgkmcnt(0)" ::: "memory");
  __builtin_amdgcn_s_barrier();

  // ---- step 3: stage A(t+1) (256x64 bf16 = 2048 chunks, 4/thread) ----
  {
    const int s0n = ((t + 1) & (NT - 1)) * 64;
#pragma unroll
    for (int i = 0; i < 4; ++i) {
      int ch   = i * 512 + tid;
      int m    = ch >> 3;
      int slot = (ch & 7) ^ (m & 7);
      const ushort_t* src = xTc + (size_t)m * SEQ + s0n + slot * 8;
      __builtin_amdgcn_global_load_lds(
          (u32_gl*)src, (u32_ld*)(Alds + (P ^ 1) * 32768 + ch * 16), 16, 0, 0);
    }
  }

  // ---- step 4: drain A(t); leave [W(t+1):8, A(t+1):4] = 12 ----
  asm volatile("s_waitcnt vmcnt(12)" ::: "memory");
  SB();

  // ---- step 5: all waves' A(t) landed ----
  __builtin_amdgcn_s_barrier();

  // ---- step 6: compute from parity-P buffers (single-bfr liveness) ----
#pragma unroll
  for (int ks = 0; ks < 2; ++ks) {
    bf16x8 af[4];
#pragma unroll
    for (int mi = 0; mi < 4; ++mi) {
      int m_local = wr * 64 + mi * 16 + lm;
      int byte = (m_local * 128 + (ks * 4 + g) * 16) ^ ((m_local & 7) << 4);
      af[mi] = *reinterpret_cast<const bf16x8*>(Alds + P * 32768 + byte);
    }
#pragma unroll
    for (int ni = 0; ni < 8; ++ni) {
      int e_local = wc * 128 + ni * 16 + lm;
      int byte = (e_local * 128 + (ks * 4 + g) * 16) ^ ((e_local & 7) << 4);
      bf16x8 bfr = *reinterpret_cast<const bf16x8*>(Blds + P * 32768 + byte);
#pragma unroll
      for (int mi = 0; mi < 4; ++mi)
        acc[mi][ni] = __builtin_amdgcn_mfma_f32_16x16x32_bf16(
            af[mi], bfr, acc[mi][ni], 0, 0, 0);
    }
  }
}

__global__ __launch_bounds__(512, 2) void grouped_gemm_pipe(
    const ushort_t* __restrict__ xT,  // (C,B,S) bf16
    const float* __restrict__ W,      // (C,S,E) f32
    const float* __restrict__ bias,   // (C,E) f32
    float* __restrict__ out) {        // (B,C,E) f32
  __shared__ ushort_t AldsU[2][256 * 64];  // 64 KB
  __shared__ ushort_t BldsU[2][256 * 64];  // 64 KB -> 128 KB total, 1 blk/CU

  // Bijective XCD-chunked swizzle: nwg = 256, 32 per XCD
  // (all 8 e-tiles of a channel on one XCD -> A slice L2-resident).
  const int bid = (blockIdx.x & 7) * 32 + (blockIdx.x >> 3);
  const int c   = bid >> 3;          // 0..31
  const int et  = bid & 7;
  const int e0  = et * 256;

  const int tid  = threadIdx.x;
  const int w    = tid >> 6;
  const int wr   = w >> 1;           // 0..3 m-quadrant (64 rows)
  const int wc   = w & 1;            // 0..1 e-half (128 cols)
  const int lane = tid & 63;
  const int g    = lane >> 4;
  const int lm   = lane & 15;

  const float* Wc = W + (size_t)c * SEQ * EMB;
  const ushort_t* xTc = xT + (size_t)c * (BATCH * SEQ);
  char* Alds = (char*)&AldsU[0][0];
  char* Blds = (char*)&BldsU[0][0];

  f32x4 wv[2][8];
  f32x4 acc[4][8];
#pragma unroll
  for (int i = 0; i < 4; ++i)
#pragma unroll
    for (int j = 0; j < 8; ++j) acc[i][j] = (f32x4){0.f, 0.f, 0.f, 0.f};

  // ---- prologue: issue W(0) (8 instrs), then gl_lds A(0) (4) -> queue 12 ----
  {
    const int s4  = tid >> 6;
    const int e16 = tid & 63;
    const float* wp = Wc + e0 + e16 * 4;
#pragma unroll
    for (int q = 0; q < 2; ++q)
#pragma unroll
      for (int j = 0; j < 4; ++j)
        wv[0][q * 4 + j] =
            *reinterpret_cast<const f32x4*>(wp + (size_t)((s4 + 8 * q) * 4 + j) * EMB);
    SB();
#pragma unroll
    for (int i = 0; i < 4; ++i) {
      int ch   = i * 512 + tid;
      int m    = ch >> 3;
      int slot = (ch & 7) ^ (m & 7);
      const ushort_t* src = xTc + (size_t)m * SEQ + slot * 8;
      __builtin_amdgcn_global_load_lds(
          (u32_gl*)src, (u32_ld*)(Alds + ch * 16), 16, 0, 0);
    }
    SB();
  }

  // ---- main loop, unroll-by-2 for compile-time parity ----
  for (int t = 0; t < NT; t += 2) {
    gemm_iter<0>(t,     xTc, Wc, Alds, Blds, wv, acc, tid, wr, wc, g, lm, e0);
    gemm_iter<1>(t + 1, xTc, Wc, Alds, Blds, wv, acc, tid, wr, wc, g, lm, e0);
  }

  // drain wrapped prefetch before epilogue
  asm volatile("s_waitcnt vmcnt(0)" ::: "memory");

  // ---- epilogue: bias + ReLU; D: col=lane&15, row=(lane>>4)*4+reg ----
  const float* bc = bias + (size_t)c * EMB;
#pragma unroll
  for (int ni = 0; ni < 8; ++ni) {
    const int e = e0 + wc * 128 + ni * 16 + lm;
    const float bv = bc[e];
#pragma unroll
    for (int mi = 0; mi < 4; ++mi) {
      f32x4 a = acc[mi][ni];
      const int mbase = wr * 64 + mi * 16 + g * 4;
#pragma unroll
      for (int r = 0; r < 4; ++r) {
        float v = a[r] + bv;
        v = fmaxf(v, 0.f);
        out[((size_t)(mbase + r) * NC + c) * EMB + e] = v;
      }
    }
  }
}

// ---------------------------------------------------------------------------
// Fallback (no workspace): round-1 style, A loaded strided from x directly.
// ---------------------------------------------------------------------------
__global__ __launch_bounds__(256, 2) void grouped_gemm_fallback(
    const float* __restrict__ x, const float* __restrict__ W,
    const float* __restrict__ bias, float* __restrict__ out) {
  __shared__ ushort_t Alds[128 * 64];
  __shared__ ushort_t Blds[128 * 64];
  const int bid = blockIdx.x;
  const int c   = bid >> 5;
  const int et  = (bid >> 1) & 15;
  const int bt  = bid & 1;
  const int b0  = bt * 128;
  const int e0  = et * 128;
  const int tid  = threadIdx.x;
  const int w    = tid >> 6;
  const int wr   = w >> 1;
  const int wc   = w & 1;
  const int lane = tid & 63;
  const int g    = lane >> 4;
  const int lm   = lane & 15;
  const float* Wc = W + (size_t)c * SEQ * EMB;
  const int srow8 = tid >> 5;
  const int e4    = tid & 31;
  f32x4 acc[4][4];
#pragma unroll
  for (int i = 0; i < 4; ++i)
#pragma unroll
    for (int j = 0; j < 4; ++j) acc[i][j] = (f32x4){0.f, 0.f, 0.f, 0.f};
  for (int s0 = 0; s0 < SEQ; s0 += 64) {
#pragma unroll
    for (int i = 0; i < 4; ++i) {
      int ch   = i * 256 + tid;
      int m    = ch >> 3;
      int slot = (ch & 7) ^ (m & 7);
      const float* src = x + (size_t)(b0 + m) * (SEQ * NC)
                           + (size_t)(s0 + slot * 8) * NC + c;
      unsigned int q[4];
#pragma unroll
      for (int p = 0; p < 4; ++p) {
        unsigned int h0 = f2bf(src[(2 * p + 0) * NC]);
        unsigned int h1 = f2bf(src[(2 * p + 1) * NC]);
        q[p] = h0 | (h1 << 16);
      }
      *reinterpret_cast<uint4*>((char*)&Alds[0] + ch * 16) =
          make_uint4(q[0], q[1], q[2], q[3]);
    }
    {
      const float* wp = Wc + (size_t)(s0 + srow8 * 8) * EMB + e0 + e4 * 4;
      f32x4 wvv[8];
#pragma unroll
      for (int r = 0; r < 8; ++r)
        wvv[r] = *reinterpret_cast<const f32x4*>(wp + (size_t)r * EMB);
#pragma unroll
      for (int i = 0; i < 4; ++i) {
        const int e_local = e4 * 4 + i;
        unsigned int q0 = f2bf(wvv[0][i]) | (f2bf(wvv[1][i]) << 16);
        unsigned int q1 = f2bf(wvv[2][i]) | (f2bf(wvv[3][i]) << 16);
        unsigned int q2 = f2bf(wvv[4][i]) | (f2bf(wvv[5][i]) << 16);
        unsigned int q3 = f2bf(wvv[6][i]) | (f2bf(wvv[7][i]) << 16);
        int byte = (e_local * 128 + srow8 * 16) ^ ((e_local & 7) << 4);
        *reinterpret_cast<uint4*>((char*)&Blds[0] + byte) =
            make_uint4(q0, q1, q2, q3);
      }
    }
    __syncthreads();
#pragma unroll
    for (int ks = 0; ks < 2; ++ks) {
      bf16x8 af[4], bfr[4];
#pragma unroll
      for (int mi = 0; mi < 4; ++mi) {
        int m_local = wr * 64 + mi * 16 + lm;
        int byte = (m_local * 128 + (ks * 4 + g) * 16) ^ ((m_local & 7) << 4);
        af[mi] = *reinterpret_cast<const bf16x8*>((const char*)&Alds[0] + byte);
      }
#pragma unroll
      for (int ni = 0; ni < 4; ++ni) {
        int e_local = wc * 64 + ni * 16 + lm;
        int byte = (e_local * 128 + (ks * 4 + g) * 16) ^ ((e_local & 7) << 4);
        bfr[ni] = *reinterpret_cast<const bf16x8*>((const char*)&Blds[0] + byte);
      }
#pragma unroll
      for (int mi = 0; mi < 4; ++mi)
#pragma unroll
        for (int ni = 0; ni < 4; ++ni)
          acc[mi][ni] = __builtin_amdgcn_mfma_f32_16x16x32_bf16(
              af[mi], bfr[ni], acc[mi][ni], 0, 0, 0);
    }
    __syncthreads();
  }
  const float* bc = bias + (size_t)c * EMB;
#pragma unroll
  for (int ni = 0; ni < 4; ++ni) {
    const int e = e0 + wc * 64 + ni * 16 + lm;
    const float bv = bc[e];
#pragma unroll
    for (int mi = 0; mi < 4; ++mi) {
      f32x4 a = acc[mi][ni];
      const int mbase = b0 + wr * 64 + mi * 16 + g * 4;
#pragma unroll
      for (int r = 0; r < 4; ++r) {
        float v = a[r] + bv;
        v = fmaxf(v, 0.f);
        out[((size_t)(mbase + r) * NC + c) * EMB + e] = v;
      }
    }
  }
}

extern "C" void kernel_launch(void* const* d_in, const int* in_sizes, int n_in,
                              void* d_out, int out_size, void* d_ws, size_t ws_size,
                              hipStream_t stream) {
  const float* x    = (const float*)d_in[0];
  const float* W    = (const float*)d_in[1];
  const float* bias = (const float*)d_in[2];
  float* out        = (float*)d_out;

  const size_t xT_bytes = (size_t)NC * BATCH * SEQ * sizeof(ushort_t);

  if (ws_size >= xT_bytes) {
    ushort_t* xT = (ushort_t*)d_ws;
    transpose_x_kernel<<<BATCH * (SEQ / 64), 256, 0, stream>>>(x, xT);
    grouped_gemm_pipe<<<NC * (EMB / 256), 512, 0, stream>>>(xT, W, bias, out);
  } else {
    grouped_gemm_fallback<<<NC * 2 * (EMB / 128), 256, 0, stream>>>(x, W, bias, out);
  }
}

// Round 9
// 148.749 us; speedup vs baseline: 2.6873x; 2.6873x over previous
//
#include <hip/hip_runtime.h>

#define BATCH 256
#define SEQ   2048
#define NC    32
#define EMB   2048
#define NT    32          // SEQ / BK, BK = 64

typedef unsigned short ushort_t;
using f32x4  = __attribute__((ext_vector_type(4))) float;
using bf16x8 = __attribute__((ext_vector_type(8))) short;

using u32_gl = __attribute__((address_space(1))) const unsigned int;
using u32_ld = __attribute__((address_space(3))) unsigned int;

__device__ __forceinline__ unsigned int f2bf(float f) {
  unsigned int u = __float_as_uint(f);
  u += 0x7FFFu + ((u >> 16) & 1u);   // RNE (finite inputs)
  return u >> 16;
}

#define SB() __builtin_amdgcn_sched_barrier(0)

// ---------------------------------------------------------------------------
// x: (B, S, C) f32  ->  xT: (C, B, S) bf16
// ---------------------------------------------------------------------------
__global__ __launch_bounds__(256) void transpose_x_kernel(
    const float* __restrict__ x, ushort_t* __restrict__ xT) {
  __shared__ float tile[64][33];
  const int b  = blockIdx.x >> 5;
  const int st = blockIdx.x & 31;
  const int t  = threadIdx.x;
  const float* src = x + ((size_t)b * SEQ + (size_t)st * 64) * NC;
#pragma unroll
  for (int i = 0; i < 2; ++i) {
    int idx = t + i * 256;
    float4 v = reinterpret_cast<const float4*>(src)[idx];
    int s = idx >> 3;
    int c = (idx & 7) * 4;
    tile[s][c + 0] = v.x; tile[s][c + 1] = v.y;
    tile[s][c + 2] = v.z; tile[s][c + 3] = v.w;
  }
  __syncthreads();
  const int c  = t >> 3;
  const int si = (t & 7) * 8;
  unsigned int q[4];
#pragma unroll
  for (int p = 0; p < 4; ++p) {
    unsigned int h0 = f2bf(tile[si + 2 * p + 0][c]);
    unsigned int h1 = f2bf(tile[si + 2 * p + 1][c]);
    q[p] = h0 | (h1 << 16);
  }
  ushort_t* dst = xT + (size_t)c * (BATCH * SEQ) + (size_t)b * SEQ + st * 64 + si;
  *reinterpret_cast<uint4*>(dst) = make_uint4(q[0], q[1], q[2], q[3]);
}

// ---------------------------------------------------------------------------
// R3 champion geometry/schedule (BM=256 / BN=128 / BK=64, 512 thr = 8 waves
// as 4m x 2e, A dbuf 64 KB + B dbuf 32 KB = 96 KB, 2 barriers/iter, counted
// vmcnt), with the B-write bank conflict FIXED:
//   W-load ownership: thread owns e-cols {e4, e4+32, e4+64, e4+96} x 4 s-rows
//   (16 scalar NT loads, 2x128B coalesced segments per instr). Per convert
//   write instr, lanes cover 32 CONSECUTIVE e-rows -> key (e&7) spans 0..7 ->
//   ds_write 2-way (free) instead of ~16-way. Read path identical to R3.
// Steady vmem queue entering iter t: [W(t):16, A(t):4] = 20.
// ---------------------------------------------------------------------------
template <int P>
__device__ __forceinline__ void gemm_iter(
    int t, const ushort_t* __restrict__ xTc, const float* __restrict__ Wc,
    char* Alds, char* Blds, float (&wvs)[2][16], f32x4 (&acc)[4][4],
    int tid, int wr, int wc, int g, int lm, int e0) {
  const int srow4 = tid >> 5;        // 0..15 -> W s-rows srow4*4..+3
  const int e4    = tid & 31;        // 0..31 -> base e column

  // ---- step 0: issue W(t+1): 16 NT scalar loads (r x i grid) ----
  {
    const int tn = (t + 1) & (NT - 1);
    const float* wp = Wc + (size_t)(tn * 64 + srow4 * 4) * EMB + e0 + e4;
#pragma unroll
    for (int r = 0; r < 4; ++r)
#pragma unroll
      for (int i = 0; i < 4; ++i)
        wvs[P ^ 1][r * 4 + i] =
            __builtin_nontemporal_load(wp + (size_t)r * EMB + 32 * i);
  }
  SB();

  // ---- step 1: W(t) ready; leave [A(t):4, W(t+1):16] in flight ----
  asm volatile("s_waitcnt vmcnt(20)" ::: "memory");

  // ---- step 2: convert W(t) -> Blds[P]; write instr i covers rows e4+32i
  //      (32 consecutive e across lanes -> conflict-free with key (e&7)) ----
#pragma unroll
  for (int i = 0; i < 4; ++i) {
    const int e_local = e4 + 32 * i;
    unsigned int lo = f2bf(wvs[P][0 * 4 + i]) | (f2bf(wvs[P][1 * 4 + i]) << 16);
    unsigned int hi = f2bf(wvs[P][2 * 4 + i]) | (f2bf(wvs[P][3 * 4 + i]) << 16);
    int byte = (e_local * 128 + srow4 * 8) ^ ((e_local & 7) << 4);
    *reinterpret_cast<uint2*>(Blds + P * 16384 + byte) = make_uint2(lo, hi);
  }
  asm volatile("s_waitcnt lgkmcnt(0)" ::: "memory");
  __builtin_amdgcn_s_barrier();

  // ---- step 3: stage A(t+1) (256x64 bf16 = 2048 chunks, 4/thread) ----
  {
    const int s0n = ((t + 1) & (NT - 1)) * 64;
#pragma unroll
    for (int i = 0; i < 4; ++i) {
      int ch   = i * 512 + tid;
      int m    = ch >> 3;
      int slot = (ch & 7) ^ (m & 7);
      const ushort_t* src = xTc + (size_t)m * SEQ + s0n + slot * 8;
      __builtin_amdgcn_global_load_lds(
          (u32_gl*)src, (u32_ld*)(Alds + (P ^ 1) * 32768 + ch * 16), 16, 0, 0);
    }
  }

  // ---- step 4: drain A(t); leave [W(t+1):16, A(t+1):4] = 20 ----
  asm volatile("s_waitcnt vmcnt(20)" ::: "memory");
  SB();

  // ---- step 5: all waves' A(t) landed ----
  __builtin_amdgcn_s_barrier();

  // ---- step 6: compute from parity-P buffers (identical to R3) ----
#pragma unroll
  for (int ks = 0; ks < 2; ++ks) {
    bf16x8 af[4], bfr[4];
#pragma unroll
    for (int mi = 0; mi < 4; ++mi) {
      int m_local = wr * 64 + mi * 16 + lm;
      int byte = (m_local * 128 + (ks * 4 + g) * 16) ^ ((m_local & 7) << 4);
      af[mi] = *reinterpret_cast<const bf16x8*>(Alds + P * 32768 + byte);
    }
#pragma unroll
    for (int ni = 0; ni < 4; ++ni) {
      int e_local = wc * 64 + ni * 16 + lm;
      int byte = (e_local * 128 + (ks * 4 + g) * 16) ^ ((e_local & 7) << 4);
      bfr[ni] = *reinterpret_cast<const bf16x8*>(Blds + P * 16384 + byte);
    }
#pragma unroll
    for (int mi = 0; mi < 4; ++mi)
#pragma unroll
      for (int ni = 0; ni < 4; ++ni)
        acc[mi][ni] = __builtin_amdgcn_mfma_f32_16x16x32_bf16(
            af[mi], bfr[ni], acc[mi][ni], 0, 0, 0);
  }
}

__global__ __launch_bounds__(512, 2) void grouped_gemm_pipe(
    const ushort_t* __restrict__ xT,  // (C,B,S) bf16
    const float* __restrict__ W,      // (C,S,E) f32
    const float* __restrict__ bias,   // (C,E) f32
    float* __restrict__ out) {        // (B,C,E) f32
  __shared__ ushort_t AldsU[2][256 * 64];  // 64 KB
  __shared__ ushort_t BldsU[2][128 * 64];  // 32 KB -> 96 KB total

  // Bijective XCD-chunked swizzle: nwg = 512, 64 per XCD
  // (all 16 e-tiles of a channel on one XCD -> A slice L2-shared).
  const int bid = (blockIdx.x & 7) * 64 + (blockIdx.x >> 3);
  const int c   = bid >> 4;
  const int et  = bid & 15;
  const int e0  = et * 128;

  const int tid  = threadIdx.x;
  const int w    = tid >> 6;
  const int wr   = w >> 1;           // 0..3 m-quadrant
  const int wc   = w & 1;            // 0..1 e-half
  const int lane = tid & 63;
  const int g    = lane >> 4;
  const int lm   = lane & 15;

  const float* Wc = W + (size_t)c * SEQ * EMB;
  const ushort_t* xTc = xT + (size_t)c * (BATCH * SEQ);
  char* Alds = (char*)&AldsU[0][0];
  char* Blds = (char*)&BldsU[0][0];

  float wvs[2][16];
  f32x4 acc[4][4];
#pragma unroll
  for (int i = 0; i < 4; ++i)
#pragma unroll
    for (int j = 0; j < 4; ++j) acc[i][j] = (f32x4){0.f, 0.f, 0.f, 0.f};

  // ---- prologue: issue W(0):16, then gl_lds A(0):4 -> queue = 20 ----
  {
    const int srow4 = tid >> 5;
    const int e4    = tid & 31;
    const float* wp = Wc + (size_t)(srow4 * 4) * EMB + e0 + e4;
#pragma unroll
    for (int r = 0; r < 4; ++r)
#pragma unroll
      for (int i = 0; i < 4; ++i)
        wvs[0][r * 4 + i] =
            __builtin_nontemporal_load(wp + (size_t)r * EMB + 32 * i);
    SB();
#pragma unroll
    for (int i = 0; i < 4; ++i) {
      int ch   = i * 512 + tid;
      int m    = ch >> 3;
      int slot = (ch & 7) ^ (m & 7);
      const ushort_t* src = xTc + (size_t)m * SEQ + slot * 8;
      __builtin_amdgcn_global_load_lds(
          (u32_gl*)src, (u32_ld*)(Alds + ch * 16), 16, 0, 0);
    }
    SB();
  }

  // ---- main loop, unroll-by-2 for compile-time parity ----
  for (int t = 0; t < NT; t += 2) {
    gemm_iter<0>(t,     xTc, Wc, Alds, Blds, wvs, acc, tid, wr, wc, g, lm, e0);
    gemm_iter<1>(t + 1, xTc, Wc, Alds, Blds, wvs, acc, tid, wr, wc, g, lm, e0);
  }

  // drain wrapped prefetch before epilogue
  asm volatile("s_waitcnt vmcnt(0)" ::: "memory");

  // ---- epilogue: bias + ReLU; NT stores (out is write-once) ----
  const float* bc = bias + (size_t)c * EMB;
#pragma unroll
  for (int ni = 0; ni < 4; ++ni) {
    const int e = e0 + wc * 64 + ni * 16 + lm;
    const float bv = bc[e];
#pragma unroll
    for (int mi = 0; mi < 4; ++mi) {
      f32x4 a = acc[mi][ni];
      const int mbase = wr * 64 + mi * 16 + g * 4;
#pragma unroll
      for (int r = 0; r < 4; ++r) {
        float v = a[r] + bv;
        v = fmaxf(v, 0.f);
        __builtin_nontemporal_store(
            v, out + ((size_t)(mbase + r) * NC + c) * EMB + e);
      }
    }
  }
}

// ---------------------------------------------------------------------------
// Fallback (no workspace): round-1 style, A loaded strided from x directly.
// ---------------------------------------------------------------------------
__global__ __launch_bounds__(256, 2) void grouped_gemm_fallback(
    const float* __restrict__ x, const float* __restrict__ W,
    const float* __restrict__ bias, float* __restrict__ out) {
  __shared__ ushort_t Alds[128 * 64];
  __shared__ ushort_t Blds[128 * 64];
  const int bid = blockIdx.x;
  const int c   = bid >> 5;
  const int et  = (bid >> 1) & 15;
  const int bt  = bid & 1;
  const int b0  = bt * 128;
  const int e0  = et * 128;
  const int tid  = threadIdx.x;
  const int w    = tid >> 6;
  const int wr   = w >> 1;
  const int wc   = w & 1;
  const int lane = tid & 63;
  const int g    = lane >> 4;
  const int lm   = lane & 15;
  const float* Wc = W + (size_t)c * SEQ * EMB;
  const int srow8 = tid >> 5;
  const int e4    = tid & 31;
  f32x4 acc[4][4];
#pragma unroll
  for (int i = 0; i < 4; ++i)
#pragma unroll
    for (int j = 0; j < 4; ++j) acc[i][j] = (f32x4){0.f, 0.f, 0.f, 0.f};
  for (int s0 = 0; s0 < SEQ; s0 += 64) {
#pragma unroll
    for (int i = 0; i < 4; ++i) {
      int ch   = i * 256 + tid;
      int m    = ch >> 3;
      int slot = (ch & 7) ^ (m & 7);
      const float* src = x + (size_t)(b0 + m) * (SEQ * NC)
                           + (size_t)(s0 + slot * 8) * NC + c;
      unsigned int q[4];
#pragma unroll
      for (int p = 0; p < 4; ++p) {
        unsigned int h0 = f2bf(src[(2 * p + 0) * NC]);
        unsigned int h1 = f2bf(src[(2 * p + 1) * NC]);
        q[p] = h0 | (h1 << 16);
      }
      *reinterpret_cast<uint4*>((char*)&Alds[0] + ch * 16) =
          make_uint4(q[0], q[1], q[2], q[3]);
    }
    {
      const float* wp = Wc + (size_t)(s0 + srow8 * 8) * EMB + e0 + e4 * 4;
      f32x4 wvv[8];
#pragma unroll
      for (int r = 0; r < 8; ++r)
        wvv[r] = *reinterpret_cast<const f32x4*>(wp + (size_t)r * EMB);
#pragma unroll
      for (int i = 0; i < 4; ++i) {
        const int e_local = e4 * 4 + i;
        unsigned int q0 = f2bf(wvv[0][i]) | (f2bf(wvv[1][i]) << 16);
        unsigned int q1 = f2bf(wvv[2][i]) | (f2bf(wvv[3][i]) << 16);
        unsigned int q2 = f2bf(wvv[4][i]) | (f2bf(wvv[5][i]) << 16);
        unsigned int q3 = f2bf(wvv[6][i]) | (f2bf(wvv[7][i]) << 16);
        int byte = (e_local * 128 + srow8 * 16) ^ ((e_local & 7) << 4);
        *reinterpret_cast<uint4*>((char*)&Blds[0] + byte) =
            make_uint4(q0, q1, q2, q3);
      }
    }
    __syncthreads();
#pragma unroll
    for (int ks = 0; ks < 2; ++ks) {
      bf16x8 af[4], bfr[4];
#pragma unroll
      for (int mi = 0; mi < 4; ++mi) {
        int m_local = wr * 64 + mi * 16 + lm;
        int byte = (m_local * 128 + (ks * 4 + g) * 16) ^ ((m_local & 7) << 4);
        af[mi] = *reinterpret_cast<const bf16x8*>((const char*)&Alds[0] + byte);
      }
#pragma unroll
      for (int ni = 0; ni < 4; ++ni) {
        int e_local = wc * 64 + ni * 16 + lm;
        int byte = (e_local * 128 + (ks * 4 + g) * 16) ^ ((e_local & 7) << 4);
        bfr[ni] = *reinterpret_cast<const bf16x8*>((const char*)&Blds[0] + byte);
      }
#pragma unroll
      for (int mi = 0; mi < 4; ++mi)
#pragma unroll
        for (int ni = 0; ni < 4; ++ni)
          acc[mi][ni] = __builtin_amdgcn_mfma_f32_16x16x32_bf16(
              af[mi], bfr[ni], acc[mi][ni], 0, 0, 0);
    }
    __syncthreads();
  }
  const float* bc = bias + (size_t)c * EMB;
#pragma unroll
  for (int ni = 0; ni < 4; ++ni) {
    const int e = e0 + wc * 64 + ni * 16 + lm;
    const float bv = bc[e];
#pragma unroll
    for (int mi = 0; mi < 4; ++mi) {
      f32x4 a = acc[mi][ni];
      const int mbase = b0 + wr * 64 + mi * 16 + g * 4;
#pragma unroll
      for (int r = 0; r < 4; ++r) {
        float v = a[r] + bv;
        v = fmaxf(v, 0.f);
        out[((size_t)(mbase + r) * NC + c) * EMB + e] = v;
      }
    }
  }
}

extern "C" void kernel_launch(void* const* d_in, const int* in_sizes, int n_in,
                              void* d_out, int out_size, void* d_ws, size_t ws_size,
                              hipStream_t stream) {
  const float* x    = (const float*)d_in[0];
  const float* W    = (const float*)d_in[1];
  const float* bias = (const float*)d_in[2];
  float* out        = (float*)d_out;

  const size_t xT_bytes = (size_t)NC * BATCH * SEQ * sizeof(ushort_t);

  if (ws_size >= xT_bytes) {
    ushort_t* xT = (ushort_t*)d_ws;
    transpose_x_kernel<<<BATCH * (SEQ / 64), 256, 0, stream>>>(x, xT);
    grouped_gemm_pipe<<<NC * (EMB / 128), 512, 0, stream>>>(xT, W, bias, out);
  } else {
    grouped_gemm_fallback<<<NC * 2 * (EMB / 128), 256, 0, stream>>>(x, W, bias, out);
  }
}

// Round 10
// 148.137 us; speedup vs baseline: 2.6984x; 1.0041x over previous
//
#include <hip/hip_runtime.h>

#define BATCH 256
#define SEQ   2048
#define NC    32
#define EMB   2048
#define NT    32          // SEQ / BK, BK = 64

typedef unsigned short ushort_t;
using f32x4  = __attribute__((ext_vector_type(4))) float;
using bf16x8 = __attribute__((ext_vector_type(8))) short;

using u32_gl = __attribute__((address_space(1))) const unsigned int;
using u32_ld = __attribute__((address_space(3))) unsigned int;

__device__ __forceinline__ unsigned int f2bf(float f) {
  unsigned int u = __float_as_uint(f);
  u += 0x7FFFu + ((u >> 16) & 1u);   // RNE (finite inputs)
  return u >> 16;
}

#define SB() __builtin_amdgcn_sched_barrier(0)

// ---------------------------------------------------------------------------
// x: (B, S, C) f32  ->  xT: (C, B, S) bf16
// ---------------------------------------------------------------------------
__global__ __launch_bounds__(256) void transpose_x_kernel(
    const float* __restrict__ x, ushort_t* __restrict__ xT) {
  __shared__ float tile[64][33];
  const int b  = blockIdx.x >> 5;
  const int st = blockIdx.x & 31;
  const int t  = threadIdx.x;
  const float* src = x + ((size_t)b * SEQ + (size_t)st * 64) * NC;
#pragma unroll
  for (int i = 0; i < 2; ++i) {
    int idx = t + i * 256;
    float4 v = reinterpret_cast<const float4*>(src)[idx];
    int s = idx >> 3;
    int c = (idx & 7) * 4;
    tile[s][c + 0] = v.x; tile[s][c + 1] = v.y;
    tile[s][c + 2] = v.z; tile[s][c + 3] = v.w;
  }
  __syncthreads();
  const int c  = t >> 3;
  const int si = (t & 7) * 8;
  unsigned int q[4];
#pragma unroll
  for (int p = 0; p < 4; ++p) {
    unsigned int h0 = f2bf(tile[si + 2 * p + 0][c]);
    unsigned int h1 = f2bf(tile[si + 2 * p + 1][c]);
    q[p] = h0 | (h1 << 16);
  }
  ushort_t* dst = xT + (size_t)c * (BATCH * SEQ) + (size_t)b * SEQ + st * 64 + si;
  *reinterpret_cast<uint4*>(dst) = make_uint4(q[0], q[1], q[2], q[3]);
}

// ---------------------------------------------------------------------------
// R9 champion (BM=256 / BN=128 / BK=64, 512 thr = 8 waves as 4m x 2e, A dbuf
// 64 KB + B dbuf 32 KB, counted vmcnt, conflict-free B writes via scalar-e
// W-ownership, NT load/store hints) with the sync structure reduced to ONE
// barrier per iter:
//   a. issue W(t+1)            b. vmcnt(20) -> W(t) ready
//   c. convert/write B(t)      d. vmcnt(16) -> A(t) landed (own gl_lds)
//   e. lgkmcnt(0) + s_barrier  f. issue gl_lds A(t+1) (WAR-safe post-barrier)
//   g. compute(t)
// Hazards: B(t) visibility via lgkmcnt+barrier; A(t) cross-wave visibility:
// each wave drains its own A(t) (d) before the barrier (e); A(t+1) WAR vs
// compute(t-1) separated by barrier(t); B WAR separated by barrier(t+1).
// Queue entering iter t: [W(t):16, A(t):4] = 20 (max in-flight 36 < 63).
// ---------------------------------------------------------------------------
template <int P>
__device__ __forceinline__ void gemm_iter(
    int t, const ushort_t* __restrict__ xTc, const float* __restrict__ Wc,
    char* Alds, char* Blds, float (&wvs)[2][16], f32x4 (&acc)[4][4],
    int tid, int wr, int wc, int g, int lm, int e0) {
  const int srow4 = tid >> 5;        // 0..15 -> W s-rows srow4*4..+3
  const int e4    = tid & 31;        // 0..31 -> base e column

  // ---- a. issue W(t+1): 16 NT scalar loads ----
  {
    const int tn = (t + 1) & (NT - 1);
    const float* wp = Wc + (size_t)(tn * 64 + srow4 * 4) * EMB + e0 + e4;
#pragma unroll
    for (int r = 0; r < 4; ++r)
#pragma unroll
      for (int i = 0; i < 4; ++i)
        wvs[P ^ 1][r * 4 + i] =
            __builtin_nontemporal_load(wp + (size_t)r * EMB + 32 * i);
  }
  SB();

  // ---- b. W(t) ready; leave [A(t):4, W(t+1):16] in flight ----
  asm volatile("s_waitcnt vmcnt(20)" ::: "memory");

  // ---- c. convert W(t) -> Blds[P] (conflict-free: lanes = 32 consec e) ----
#pragma unroll
  for (int i = 0; i < 4; ++i) {
    const int e_local = e4 + 32 * i;
    unsigned int lo = f2bf(wvs[P][0 * 4 + i]) | (f2bf(wvs[P][1 * 4 + i]) << 16);
    unsigned int hi = f2bf(wvs[P][2 * 4 + i]) | (f2bf(wvs[P][3 * 4 + i]) << 16);
    int byte = (e_local * 128 + srow4 * 8) ^ ((e_local & 7) << 4);
    *reinterpret_cast<uint2*>(Blds + P * 16384 + byte) = make_uint2(lo, hi);
  }
  SB();

  // ---- d. own A(t) gl_lds landed; leave [W(t+1):16] ----
  asm volatile("s_waitcnt vmcnt(16)" ::: "memory");

  // ---- e. single barrier (B writes + A arrival both sealed) ----
  asm volatile("s_waitcnt lgkmcnt(0)" ::: "memory");
  __builtin_amdgcn_s_barrier();

  // ---- f. stage A(t+1) early (hides HBM latency under compute) ----
  {
    const int s0n = ((t + 1) & (NT - 1)) * 64;
#pragma unroll
    for (int i = 0; i < 4; ++i) {
      int ch   = i * 512 + tid;
      int m    = ch >> 3;
      int slot = (ch & 7) ^ (m & 7);
      const ushort_t* src = xTc + (size_t)m * SEQ + s0n + slot * 8;
      __builtin_amdgcn_global_load_lds(
          (u32_gl*)src, (u32_ld*)(Alds + (P ^ 1) * 32768 + ch * 16), 16, 0, 0);
    }
  }
  SB();

  // ---- g. compute(t) from parity-P buffers ----
#pragma unroll
  for (int ks = 0; ks < 2; ++ks) {
    bf16x8 af[4], bfr[4];
#pragma unroll
    for (int mi = 0; mi < 4; ++mi) {
      int m_local = wr * 64 + mi * 16 + lm;
      int byte = (m_local * 128 + (ks * 4 + g) * 16) ^ ((m_local & 7) << 4);
      af[mi] = *reinterpret_cast<const bf16x8*>(Alds + P * 32768 + byte);
    }
#pragma unroll
    for (int ni = 0; ni < 4; ++ni) {
      int e_local = wc * 64 + ni * 16 + lm;
      int byte = (e_local * 128 + (ks * 4 + g) * 16) ^ ((e_local & 7) << 4);
      bfr[ni] = *reinterpret_cast<const bf16x8*>(Blds + P * 16384 + byte);
    }
#pragma unroll
    for (int mi = 0; mi < 4; ++mi)
#pragma unroll
      for (int ni = 0; ni < 4; ++ni)
        acc[mi][ni] = __builtin_amdgcn_mfma_f32_16x16x32_bf16(
            af[mi], bfr[ni], acc[mi][ni], 0, 0, 0);
  }
}

__global__ __launch_bounds__(512, 2) void grouped_gemm_pipe(
    const ushort_t* __restrict__ xT,  // (C,B,S) bf16
    const float* __restrict__ W,      // (C,S,E) f32
    const float* __restrict__ bias,   // (C,E) f32
    float* __restrict__ out) {        // (B,C,E) f32
  __shared__ ushort_t AldsU[2][256 * 64];  // 64 KB
  __shared__ ushort_t BldsU[2][128 * 64];  // 32 KB -> 96 KB total

  // Bijective XCD-chunked swizzle: nwg = 512, 64 per XCD
  // (all 16 e-tiles of a channel on one XCD -> A slice L2-shared).
  const int bid = (blockIdx.x & 7) * 64 + (blockIdx.x >> 3);
  const int c   = bid >> 4;
  const int et  = bid & 15;
  const int e0  = et * 128;

  const int tid  = threadIdx.x;
  const int w    = tid >> 6;
  const int wr   = w >> 1;           // 0..3 m-quadrant
  const int wc   = w & 1;            // 0..1 e-half
  const int lane = tid & 63;
  const int g    = lane >> 4;
  const int lm   = lane & 15;

  const float* Wc = W + (size_t)c * SEQ * EMB;
  const ushort_t* xTc = xT + (size_t)c * (BATCH * SEQ);
  char* Alds = (char*)&AldsU[0][0];
  char* Blds = (char*)&BldsU[0][0];

  float wvs[2][16];
  f32x4 acc[4][4];
#pragma unroll
  for (int i = 0; i < 4; ++i)
#pragma unroll
    for (int j = 0; j < 4; ++j) acc[i][j] = (f32x4){0.f, 0.f, 0.f, 0.f};

  // ---- prologue: issue W(0):16, then gl_lds A(0):4 -> queue = 20 ----
  {
    const int srow4 = tid >> 5;
    const int e4    = tid & 31;
    const float* wp = Wc + (size_t)(srow4 * 4) * EMB + e0 + e4;
#pragma unroll
    for (int r = 0; r < 4; ++r)
#pragma unroll
      for (int i = 0; i < 4; ++i)
        wvs[0][r * 4 + i] =
            __builtin_nontemporal_load(wp + (size_t)r * EMB + 32 * i);
    SB();
#pragma unroll
    for (int i = 0; i < 4; ++i) {
      int ch   = i * 512 + tid;
      int m    = ch >> 3;
      int slot = (ch & 7) ^ (m & 7);
      const ushort_t* src = xTc + (size_t)m * SEQ + slot * 8;
      __builtin_amdgcn_global_load_lds(
          (u32_gl*)src, (u32_ld*)(Alds + ch * 16), 16, 0, 0);
    }
    SB();
  }

  // ---- main loop, unroll-by-2 for compile-time parity ----
  for (int t = 0; t < NT; t += 2) {
    gemm_iter<0>(t,     xTc, Wc, Alds, Blds, wvs, acc, tid, wr, wc, g, lm, e0);
    gemm_iter<1>(t + 1, xTc, Wc, Alds, Blds, wvs, acc, tid, wr, wc, g, lm, e0);
  }

  // drain wrapped prefetch before epilogue
  asm volatile("s_waitcnt vmcnt(0)" ::: "memory");

  // ---- epilogue: bias + ReLU; NT stores (out is write-once) ----
  const float* bc = bias + (size_t)c * EMB;
#pragma unroll
  for (int ni = 0; ni < 4; ++ni) {
    const int e = e0 + wc * 64 + ni * 16 + lm;
    const float bv = bc[e];
#pragma unroll
    for (int mi = 0; mi < 4; ++mi) {
      f32x4 a = acc[mi][ni];
      const int mbase = wr * 64 + mi * 16 + g * 4;
#pragma unroll
      for (int r = 0; r < 4; ++r) {
        float v = a[r] + bv;
        v = fmaxf(v, 0.f);
        __builtin_nontemporal_store(
            v, out + ((size_t)(mbase + r) * NC + c) * EMB + e);
      }
    }
  }
}

// ---------------------------------------------------------------------------
// Fallback (no workspace): round-1 style, A loaded strided from x directly.
// ---------------------------------------------------------------------------
__global__ __launch_bounds__(256, 2) void grouped_gemm_fallback(
    const float* __restrict__ x, const float* __restrict__ W,
    const float* __restrict__ bias, float* __restrict__ out) {
  __shared__ ushort_t Alds[128 * 64];
  __shared__ ushort_t Blds[128 * 64];
  const int bid = blockIdx.x;
  const int c   = bid >> 5;
  const int et  = (bid >> 1) & 15;
  const int bt  = bid & 1;
  const int b0  = bt * 128;
  const int e0  = et * 128;
  const int tid  = threadIdx.x;
  const int w    = tid >> 6;
  const int wr   = w >> 1;
  const int wc   = w & 1;
  const int lane = tid & 63;
  const int g    = lane >> 4;
  const int lm   = lane & 15;
  const float* Wc = W + (size_t)c * SEQ * EMB;
  const int srow8 = tid >> 5;
  const int e4    = tid & 31;
  f32x4 acc[4][4];
#pragma unroll
  for (int i = 0; i < 4; ++i)
#pragma unroll
    for (int j = 0; j < 4; ++j) acc[i][j] = (f32x4){0.f, 0.f, 0.f, 0.f};
  for (int s0 = 0; s0 < SEQ; s0 += 64) {
#pragma unroll
    for (int i = 0; i < 4; ++i) {
      int ch   = i * 256 + tid;
      int m    = ch >> 3;
      int slot = (ch & 7) ^ (m & 7);
      const float* src = x + (size_t)(b0 + m) * (SEQ * NC)
                           + (size_t)(s0 + slot * 8) * NC + c;
      unsigned int q[4];
#pragma unroll
      for (int p = 0; p < 4; ++p) {
        unsigned int h0 = f2bf(src[(2 * p + 0) * NC]);
        unsigned int h1 = f2bf(src[(2 * p + 1) * NC]);
        q[p] = h0 | (h1 << 16);
      }
      *reinterpret_cast<uint4*>((char*)&Alds[0] + ch * 16) =
          make_uint4(q[0], q[1], q[2], q[3]);
    }
    {
      const float* wp = Wc + (size_t)(s0 + srow8 * 8) * EMB + e0 + e4 * 4;
      f32x4 wvv[8];
#pragma unroll
      for (int r = 0; r < 8; ++r)
        wvv[r] = *reinterpret_cast<const f32x4*>(wp + (size_t)r * EMB);
#pragma unroll
      for (int i = 0; i < 4; ++i) {
        const int e_local = e4 * 4 + i;
        unsigned int q0 = f2bf(wvv[0][i]) | (f2bf(wvv[1][i]) << 16);
        unsigned int q1 = f2bf(wvv[2][i]) | (f2bf(wvv[3][i]) << 16);
        unsigned int q2 = f2bf(wvv[4][i]) | (f2bf(wvv[5][i]) << 16);
        unsigned int q3 = f2bf(wvv[6][i]) | (f2bf(wvv[7][i]) << 16);
        int byte = (e_local * 128 + srow8 * 16) ^ ((e_local & 7) << 4);
        *reinterpret_cast<uint4*>((char*)&Blds[0] + byte) =
            make_uint4(q0, q1, q2, q3);
      }
    }
    __syncthreads();
#pragma unroll
    for (int ks = 0; ks < 2; ++ks) {
      bf16x8 af[4], bfr[4];
#pragma unroll
      for (int mi = 0; mi < 4; ++mi) {
        int m_local = wr * 64 + mi * 16 + lm;
        int byte = (m_local * 128 + (ks * 4 + g) * 16) ^ ((m_local & 7) << 4);
        af[mi] = *reinterpret_cast<const bf16x8*>((const char*)&Alds[0] + byte);
      }
#pragma unroll
      for (int ni = 0; ni < 4; ++ni) {
        int e_local = wc * 64 + ni * 16 + lm;
        int byte = (e_local * 128 + (ks * 4 + g) * 16) ^ ((e_local & 7) << 4);
        bfr[ni] = *reinterpret_cast<const bf16x8*>((const char*)&Blds[0] + byte);
      }
#pragma unroll
      for (int mi = 0; mi < 4; ++mi)
#pragma unroll
        for (int ni = 0; ni < 4; ++ni)
          acc[mi][ni] = __builtin_amdgcn_mfma_f32_16x16x32_bf16(
              af[mi], bfr[ni], acc[mi][ni], 0, 0, 0);
    }
    __syncthreads();
  }
  const float* bc = bias + (size_t)c * EMB;
#pragma unroll
  for (int ni = 0; ni < 4; ++ni) {
    const int e = e0 + wc * 64 + ni * 16 + lm;
    const float bv = bc[e];
#pragma unroll
    for (int mi = 0; mi < 4; ++mi) {
      f32x4 a = acc[mi][ni];
      const int mbase = b0 + wr * 64 + mi * 16 + g * 4;
#pragma unroll
      for (int r = 0; r < 4; ++r) {
        float v = a[r] + bv;
        v = fmaxf(v, 0.f);
        out[((size_t)(mbase + r) * NC + c) * EMB + e] = v;
      }
    }
  }
}

extern "C" void kernel_launch(void* const* d_in, const int* in_sizes, int n_in,
                              void* d_out, int out_size, void* d_ws, size_t ws_size,
                              hipStream_t stream) {
  const float* x    = (const float*)d_in[0];
  const float* W    = (const float*)d_in[1];
  const float* bias = (const float*)d_in[2];
  float* out        = (float*)d_out;

  const size_t xT_bytes = (size_t)NC * BATCH * SEQ * sizeof(ushort_t);

  if (ws_size >= xT_bytes) {
    ushort_t* xT = (ushort_t*)d_ws;
    transpose_x_kernel<<<BATCH * (SEQ / 64), 256, 0, stream>>>(x, xT);
    grouped_gemm_pipe<<<NC * (EMB / 128), 512, 0, stream>>>(xT, W, bias, out);
  } else {
    grouped_gemm_fallback<<<NC * 2 * (EMB / 128), 256, 0, stream>>>(x, W, bias, out);
  }
}